// Round 8
// baseline (229.531 us; speedup 1.0000x reference)
//
#include <hip/hip_runtime.h>
#include <hip/hip_bf16.h>
#include <math.h>

typedef unsigned short u16;
using short8 = __attribute__((ext_vector_type(8))) short;
using f32x4  = __attribute__((ext_vector_type(4))) float;
using f32x16 = __attribute__((ext_vector_type(16))) float;

#define BK 32

// ---------- helpers ----------

__device__ __forceinline__ u16 f2bf(float f) {
  union { float f; unsigned u; } v; v.f = f;
  unsigned r = v.u + 0x7FFFu + ((v.u >> 16) & 1u);   // RNE
  return (u16)(r >> 16);
}

__device__ __forceinline__ float fexp(float x) { return __expf(x); }

__device__ __forceinline__ void gld16(const void* g, void* l) {
  __builtin_amdgcn_global_load_lds(
      (const __attribute__((address_space(1))) void*)g,
      (__attribute__((address_space(3))) void*)l,
      16, 0, 0);
}

// ---------- wide GEMM core: 128x256 block tile, 4 waves of 64x128 ----------
// 32x32x16 MFMA, XOR bank-deswizzle (conflict-free: bank-quad =
// 4*(ln&1) + ((kh*2+l5)^((ln>>1)&3)) -> exactly 8 lanes per quad).
// LDS bytes/FLOP = 72KB / 2.1MFLOP = 0.034 (vs 0.046 for 64x64 wave tiles):
// the core is LDS-BW-bound, so wave-tile ratio M*N/(M+N) is the lever.
// A[*,lda], B[*,ldb]^T row-major K-contiguous bf16. As 8KB, Bs 16KB.

__device__ __forceinline__ void core_wide(const u16* __restrict__ Ag,
                                          const u16* __restrict__ Bg,
                                          int K, int lda, int ldb,
                                          u16* As, u16* Bs,
                                          f32x16 acc[2][4], int w, int l) {
  const int ln = l & 31, l5 = l >> 5;
  const int sr = w * 16 + (l >> 2);
  const int skp = (l & 3) * 8;                       // physical LDS chunk
  const int skg = ((l & 3) ^ ((l >> 3) & 3)) * 8;    // logical/global chunk
  const int wm = (w & 1) << 6, wn = (w >> 1) << 7;
  const int g = (ln >> 1) & 3;
  const int ko0 = (l5 ^ g) * 8;                      // kh=0 phys chunk
  const int ko1 = ((2 + l5) ^ g) * 8;                // kh=1 phys chunk

#pragma unroll
  for (int mt = 0; mt < 2; mt++)
#pragma unroll
    for (int nt = 0; nt < 4; nt++) acc[mt][nt] = (f32x16)0.0f;

  for (int k0 = 0; k0 < K; k0 += BK) {
    __syncthreads();
    gld16(Ag + (size_t)sr * lda + k0 + skg, As + sr * BK + skp);
    gld16(Ag + (size_t)(sr + 64) * lda + k0 + skg, As + (sr + 64) * BK + skp);
#pragma unroll
    for (int j = 0; j < 4; j++)
      gld16(Bg + (size_t)(sr + 64 * j) * ldb + k0 + skg,
            Bs + (sr + 64 * j) * BK + skp);
    __syncthreads();
    short8 af[2][2], bf[4][2];
#pragma unroll
    for (int mt = 0; mt < 2; mt++) {
      af[mt][0] = *(const short8*)(As + (wm + mt * 32 + ln) * BK + ko0);
      af[mt][1] = *(const short8*)(As + (wm + mt * 32 + ln) * BK + ko1);
    }
#pragma unroll
    for (int nt = 0; nt < 4; nt++) {
      bf[nt][0] = *(const short8*)(Bs + (wn + nt * 32 + ln) * BK + ko0);
      bf[nt][1] = *(const short8*)(Bs + (wn + nt * 32 + ln) * BK + ko1);
    }
#pragma unroll
    for (int kh = 0; kh < 2; kh++)
#pragma unroll
      for (int mt = 0; mt < 2; mt++)
#pragma unroll
        for (int nt = 0; nt < 4; nt++)
          acc[mt][nt] = __builtin_amdgcn_mfma_f32_32x32x16_bf16(
              af[mt][kh], bf[nt][kh], acc[mt][nt], 0, 0, 0);
  }
}

// ---------- merged conversion kernel (+ lsum zeroing) ----------

__global__ __launch_bounds__(256) void k_conv(
    const float* __restrict__ x, u16* __restrict__ xb,
    const float* __restrict__ Wq, const float* __restrict__ Wk,
    const float* __restrict__ Wv, const float* __restrict__ bq,
    const float* __restrict__ bk, const float* __restrict__ bv,
    u16* __restrict__ Wt, float* __restrict__ bcat,
    float* __restrict__ lsum) {
  const int bid = blockIdx.x;
  if (bid < 4096) {
    int i = bid * 256 + threadIdx.x;
    float4 v = ((const float4*)x)[i];
    ushort4 o;
    o.x = f2bf(v.x); o.y = f2bf(v.y); o.z = f2bf(v.z); o.w = f2bf(v.w);
    ((ushort4*)xb)[i] = o;
  } else if (bid < 5632) {
    int i = (bid - 4096) * 256 + threadIdx.x;
    int nn = i >> 8, e = i & 255;
    int sel = nn >> 9, c = nn & 511;
    const float* W = (sel == 0) ? Wq : (sel == 1) ? Wk : Wv;
    Wt[i] = f2bf(W[e * 512 + c]);
    if (e == 0) {
      const float* bb = (sel == 0) ? bq : (sel == 1) ? bk : bv;
      bcat[nn] = bb[c];
    }
  } else {
    int i = (bid - 5632) * 256 + threadIdx.x;   // 64 blocks -> 16384 floats
    lsum[i] = 0.0f;
  }
}

// ---------- projection: A-resident shared-slab GEMM (R7, unchanged) ----------

__global__ __launch_bounds__(256) void k_proj(
    const u16* __restrict__ xb, const u16* __restrict__ Wt,
    const float* __restrict__ bcat, u16* __restrict__ qb,
    u16* __restrict__ kb, u16* __restrict__ vtb) {
  __shared__ __align__(16) u16 As8[8 * 4096];  // 64 KB: 8 windows x [128][32]
  __shared__ __align__(16) u16 Bs[4096];       // 8 KB
  const int bm = blockIdx.y * 128;
  const int bnq = blockIdx.x;                  // 0..3: 128-col quarter of 512
  const int tid = threadIdx.x, w = tid >> 6, l = tid & 63;
  const int wm = (w & 1) << 6, wn = (w >> 1) << 6;
  const int ln = l & 15, lq = l >> 4;
  const int sr0 = w * 16 + (l >> 2);
  const int sr1 = 64 + sr0;
  const int skp = (l & 3) * 8;
  const int skg = ((l & 3) ^ ((l >> 3) & 3)) * 8;
  const int kro = (lq ^ ((ln >> 1) & 3)) * 8;

#pragma unroll
  for (int kw = 0; kw < 8; kw++) {
    gld16(xb + (size_t)(bm + sr0) * 256 + kw * 32 + skg,
          As8 + kw * 4096 + sr0 * BK + skp);
    gld16(xb + (size_t)(bm + sr1) * 256 + kw * 32 + skg,
          As8 + kw * 4096 + sr1 * BK + skp);
  }

  const int b = bm >> 11, t0 = bm & 2047;
  const int cb = bnq * 128;

  for (int p = 0; p < 3; p++) {
    const u16* Bg = Wt + (size_t)(p * 512 + cb) * 256;
    f32x4 acc[4][4];
#pragma unroll
    for (int mt = 0; mt < 4; mt++)
#pragma unroll
      for (int nt = 0; nt < 4; nt++) acc[mt][nt] = (f32x4)0.0f;

#pragma unroll
    for (int it = 0; it < 8; it++) {
      __syncthreads();
      gld16(Bg + (size_t)sr0 * 256 + it * 32 + skg, Bs + sr0 * BK + skp);
      gld16(Bg + (size_t)sr1 * 256 + it * 32 + skg, Bs + sr1 * BK + skp);
      __syncthreads();
      const u16* Aw = As8 + it * 4096;
      short8 af[4], bf[4];
#pragma unroll
      for (int mt = 0; mt < 4; mt++)
        af[mt] = *(const short8*)(Aw + (wm + mt * 16 + ln) * BK + kro);
#pragma unroll
      for (int nt = 0; nt < 4; nt++)
        bf[nt] = *(const short8*)(Bs + (wn + nt * 16 + ln) * BK + kro);
#pragma unroll
      for (int mt = 0; mt < 4; mt++)
#pragma unroll
        for (int nt = 0; nt < 4; nt++)
          acc[mt][nt] = __builtin_amdgcn_mfma_f32_16x16x32_bf16(
              af[mt], bf[nt], acc[mt][nt], 0, 0, 0);
    }

    if (p < 2) {
      u16* dst = p ? kb : qb;
#pragma unroll
      for (int mt = 0; mt < 4; mt++)
#pragma unroll
        for (int r = 0; r < 4; r++) {
          int row = bm + wm + mt * 16 + lq * 4 + r;
#pragma unroll
          for (int nt = 0; nt < 4; nt++) {
            int col = wn + nt * 16 + ln;
            float v = acc[mt][nt][r] + bcat[p * 512 + cb + col];
            float ov = (p == 0) ? __builtin_amdgcn_rcpf(1.0f + fexp(-v)) : v;
            dst[(size_t)row * 512 + cb + col] = f2bf(ov);
          }
        }
    } else {
      u16* tr = As8;                            // reuse dead A slab
#pragma unroll
      for (int h = 0; h < 2; h++) {
        __syncthreads();
        if ((w & 1) == h) {
#pragma unroll
          for (int mt = 0; mt < 4; mt++)
#pragma unroll
            for (int nt = 0; nt < 4; nt++) {
              int c = wn + nt * 16 + ln;
              float bias = bcat[1024 + cb + c];
#pragma unroll
              for (int r = 0; r < 4; r++) {
                int lr = mt * 16 + lq * 4 + r;
                tr[c * 68 + lr] = f2bf(acc[mt][nt][r] + bias);
              }
            }
        }
        __syncthreads();
        int c2 = tid >> 1, half = tid & 1;
        size_t dbase = ((size_t)b * 512 + cb + c2) * 2048 + t0 + h * 64 + half * 32;
#pragma unroll
        for (int j = 0; j < 4; j++) {
          ushort4 a0 = *(const ushort4*)&tr[c2 * 68 + half * 32 + j * 8];
          ushort4 a1 = *(const ushort4*)&tr[c2 * 68 + half * 32 + j * 8 + 4];
          *(ushort4*)&vtb[dbase + j * 8] = a0;
          *(ushort4*)&vtb[dbase + j * 8 + 4] = a1;
        }
      }
    }
  }
}

// ---------- QK^T + elu + exp -> P (bf16), row sums; 128x256 tiles ----------

__global__ __launch_bounds__(256, 2) void k_qk(const u16* __restrict__ qb,
                                               const u16* __restrict__ kb,
                                               u16* __restrict__ P,
                                               float* __restrict__ lsum) {
  __shared__ __align__(16) u16 As[128 * BK];   //  8 KB
  __shared__ __align__(16) u16 Bs[256 * BK];   // 16 KB
  // bid%8 = batch = XCD; bn fastest within XCD -> kb slab (2MB) L2-resident.
  const int bid = blockIdx.x;
  const int b = bid & 7, t = bid >> 3;
  const int bm = (t >> 3) * 128, bn = (t & 7) * 256;
  const size_t ob = (size_t)b * 2048 * 512;
  const int tid = threadIdx.x, w = tid >> 6, l = tid & 63;
  f32x16 acc[2][4];
  core_wide(qb + ob + (size_t)bm * 512, kb + ob + (size_t)bn * 512,
            512, 512, 512, As, Bs, acc, w, l);

  const int wm = (w & 1) << 6, wn = (w >> 1) << 7;
  const int ln = l & 31, l5 = l >> 5;
  const float scale = 0.0625f;  // 1/sqrt(256)
#pragma unroll
  for (int mt = 0; mt < 2; mt++)
#pragma unroll
    for (int r = 0; r < 16; r++) {
      int row = bm + wm + mt * 32 + (r & 3) + 8 * (r >> 2) + 4 * l5;
      float s = 0.0f;
#pragma unroll
      for (int nt = 0; nt < 4; nt++) {
        int col = bn + wn + nt * 32 + ln;
        float v = acc[mt][nt][r] * scale;
        float e = (v > 0.0f) ? v : (fexp(v) - 1.0f);   // elu (hw exp)
        float p = fexp(e);    // unnormalized softmax (elu >= -1, no max sub)
        P[((size_t)b * 2048 + row) * 2048 + col] = f2bf(p);
        s += p;
      }
      // 32 lanes (ln) share this row; xor offsets <32 stay within the half
#pragma unroll
      for (int o = 1; o < 32; o <<= 1) s += __shfl_xor(s, o);
      if (ln == 0) atomicAdd(&lsum[b * 2048 + row], s);
    }
}

// ---------- P @ V, divide by row sum, fp32 out; 128x256 tiles ----------

__global__ __launch_bounds__(256, 2) void k_pv(const u16* __restrict__ P,
                                               const u16* __restrict__ vtb,
                                               const float* __restrict__ lsum,
                                               float* __restrict__ out) {
  __shared__ __align__(16) u16 As[128 * BK];
  __shared__ __align__(16) u16 Bs[256 * BK];
  // 256 blocks = exactly 1/CU; bid%8 = batch = XCD (vtb slab L2-resident).
  const int bid = blockIdx.x;
  const int b = bid & 7, t = bid >> 3;
  const int bm = (t >> 1) * 128, bn = (t & 1) * 256;
  const int tid = threadIdx.x, w = tid >> 6, l = tid & 63;
  f32x16 acc[2][4];
  core_wide(P  + (size_t)b * 2048 * 2048 + (size_t)bm * 2048,
            vtb + (size_t)b * 512 * 2048 + (size_t)bn * 2048,
            2048, 2048, 2048, As, Bs, acc, w, l);

  const int wm = (w & 1) << 6, wn = (w >> 1) << 7;
  const int ln = l & 31, l5 = l >> 5;
#pragma unroll
  for (int mt = 0; mt < 2; mt++)
#pragma unroll
    for (int r = 0; r < 16; r++) {
      int row = bm + wm + mt * 32 + (r & 3) + 8 * (r >> 2) + 4 * l5;
      float inv = 1.0f / lsum[b * 2048 + row];
#pragma unroll
      for (int nt = 0; nt < 4; nt++) {
        int col = bn + wn + nt * 32 + ln;
        out[((size_t)b * 2048 + row) * 512 + col] = acc[mt][nt][r] * inv;
      }
    }
}

// ---------- launch ----------

extern "C" void kernel_launch(void* const* d_in, const int* in_sizes, int n_in,
                              void* d_out, int out_size, void* d_ws, size_t ws_size,
                              hipStream_t stream) {
  const float* x  = (const float*)d_in[0];
  const float* Wq = (const float*)d_in[1];
  const float* bq = (const float*)d_in[2];
  const float* Wk = (const float*)d_in[3];
  const float* bk = (const float*)d_in[4];
  const float* Wv = (const float*)d_in[5];
  const float* bv = (const float*)d_in[6];
  float* out = (float*)d_out;
  char* ws = (char*)d_ws;

  u16*  qb   = (u16*)(ws + 0);            // 16,777,216
  u16*  kb   = (u16*)(ws + 16777216);     // 16,777,216
  u16*  vtb  = (u16*)(ws + 33554432);     // 16,777,216
  float* lsum = (float*)(ws + 50331648);  //     65,536
  u16*  P    = (u16*)(ws + 50397184);     // 67,108,864 (ends 117,506,048)
  u16*  xb   = (u16*)(ws + 50397184);     //  8,388,608 (alias P)
  u16*  Wt   = (u16*)(ws + 58785792);     //    786,432 (alias P)
  float* bcat = (float*)(ws + 59572224);  //      6,144 (alias P)

  k_conv<<<5696, 256, 0, stream>>>(x, xb, Wq, Wk, Wv, bq, bk, bv, Wt, bcat, lsum);
  k_proj<<<dim3(4, 128, 1), 256, 0, stream>>>(xb, Wt, bcat, qb, kb, vtb);
  k_qk<<<1024, 256, 0, stream>>>(qb, kb, P, lsum);
  k_pv<<<256, 256, 0, stream>>>(P, vtb, lsum, out);
}

// Round 9
// 203.166 us; speedup vs baseline: 1.1298x; 1.1298x over previous
//
#include <hip/hip_runtime.h>
#include <hip/hip_bf16.h>
#include <math.h>

typedef unsigned short u16;
using short8 = __attribute__((ext_vector_type(8))) short;
using f32x4  = __attribute__((ext_vector_type(4))) float;

#define BK 32

// ---------- helpers ----------

__device__ __forceinline__ u16 f2bf(float f) {
  union { float f; unsigned u; } v; v.f = f;
  unsigned r = v.u + 0x7FFFu + ((v.u >> 16) & 1u);   // RNE
  return (u16)(r >> 16);
}

__device__ __forceinline__ float fexp(float x) { return __expf(x); }

__device__ __forceinline__ void gld16(const void* g, void* l) {
  __builtin_amdgcn_global_load_lds(
      (const __attribute__((address_space(1))) void*)g,
      (__attribute__((address_space(3))) void*)l,
      16, 0, 0);
}

// ---------- 4-wave GEMM core: 16x16x32 MFMA, XOR deswizzle, BK=64 ----------
// 128x128 C tile of A[*,lda] @ B[*,ldb]^T, row-major K-contiguous bf16.
// Two independent 32-wide LDS windows per operand (R6-verified conflict-free
// layout in each): one barrier pair covers 32 MFMA (vs 16 at BK=32), halving
// the structural barrier-drain count. LDS 16KB+16KB -> still 4 waves/SIMD.
// K % 64 == 0.

__device__ __forceinline__ void gemm_core64(const u16* __restrict__ Ag,
                                            const u16* __restrict__ Bg,
                                            int K, int lda, int ldb,
                                            u16* As, u16* Bs,
                                            f32x4 acc[4][4], int w, int l) {
  const int wm = (w & 1) << 6, wn = (w >> 1) << 6;
  const int ln = l & 15, lq = l >> 4;
  const int sr0 = w * 16 + (l >> 2);
  const int sr1 = 64 + sr0;
  const int skp = (l & 3) * 8;                       // physical LDS chunk
  const int skg = ((l & 3) ^ ((l >> 3) & 3)) * 8;    // logical/global chunk
  const int kro = (lq ^ ((ln >> 1) & 3)) * 8;        // read-side phys chunk

#pragma unroll
  for (int mt = 0; mt < 4; mt++)
#pragma unroll
    for (int nt = 0; nt < 4; nt++) acc[mt][nt] = (f32x4)0.0f;

  for (int k0 = 0; k0 < K; k0 += 64) {
    __syncthreads();
    gld16(Ag + (size_t)sr0 * lda + k0 + skg, As + sr0 * BK + skp);
    gld16(Ag + (size_t)sr1 * lda + k0 + skg, As + sr1 * BK + skp);
    gld16(Ag + (size_t)sr0 * lda + k0 + 32 + skg, As + 4096 + sr0 * BK + skp);
    gld16(Ag + (size_t)sr1 * lda + k0 + 32 + skg, As + 4096 + sr1 * BK + skp);
    gld16(Bg + (size_t)sr0 * ldb + k0 + skg, Bs + sr0 * BK + skp);
    gld16(Bg + (size_t)sr1 * ldb + k0 + skg, Bs + sr1 * BK + skp);
    gld16(Bg + (size_t)sr0 * ldb + k0 + 32 + skg, Bs + 4096 + sr0 * BK + skp);
    gld16(Bg + (size_t)sr1 * ldb + k0 + 32 + skg, Bs + 4096 + sr1 * BK + skp);
    __syncthreads();
#pragma unroll
    for (int h = 0; h < 2; h++) {
      const u16* Ah = As + h * 4096;
      const u16* Bh = Bs + h * 4096;
      short8 af[4], bf[4];
#pragma unroll
      for (int mt = 0; mt < 4; mt++)
        af[mt] = *(const short8*)(Ah + (wm + mt * 16 + ln) * BK + kro);
#pragma unroll
      for (int nt = 0; nt < 4; nt++)
        bf[nt] = *(const short8*)(Bh + (wn + nt * 16 + ln) * BK + kro);
#pragma unroll
      for (int mt = 0; mt < 4; mt++)
#pragma unroll
        for (int nt = 0; nt < 4; nt++)
          acc[mt][nt] = __builtin_amdgcn_mfma_f32_16x16x32_bf16(
              af[mt], bf[nt], acc[mt][nt], 0, 0, 0);
    }
  }
}

// ---------- merged conversion kernel (+ lsum zeroing) ----------

__global__ __launch_bounds__(256) void k_conv(
    const float* __restrict__ x, u16* __restrict__ xb,
    const float* __restrict__ Wq, const float* __restrict__ Wk,
    const float* __restrict__ Wv, const float* __restrict__ bq,
    const float* __restrict__ bk, const float* __restrict__ bv,
    u16* __restrict__ Wt, float* __restrict__ bcat,
    float* __restrict__ lsum) {
  const int bid = blockIdx.x;
  if (bid < 4096) {
    int i = bid * 256 + threadIdx.x;
    float4 v = ((const float4*)x)[i];
    ushort4 o;
    o.x = f2bf(v.x); o.y = f2bf(v.y); o.z = f2bf(v.z); o.w = f2bf(v.w);
    ((ushort4*)xb)[i] = o;
  } else if (bid < 5632) {
    int i = (bid - 4096) * 256 + threadIdx.x;
    int nn = i >> 8, e = i & 255;
    int sel = nn >> 9, c = nn & 511;
    const float* W = (sel == 0) ? Wq : (sel == 1) ? Wk : Wv;
    Wt[i] = f2bf(W[e * 512 + c]);
    if (e == 0) {
      const float* bb = (sel == 0) ? bq : (sel == 1) ? bk : bv;
      bcat[nn] = bb[c];
    }
  } else {
    int i = (bid - 5632) * 256 + threadIdx.x;   // 64 blocks -> 16384 floats
    lsum[i] = 0.0f;
  }
}

// ---------- projection: A-resident shared-slab GEMM, BK=64 B-stream ----------

__global__ __launch_bounds__(256) void k_proj(
    const u16* __restrict__ xb, const u16* __restrict__ Wt,
    const float* __restrict__ bcat, u16* __restrict__ qb,
    u16* __restrict__ kb, u16* __restrict__ vtb) {
  __shared__ __align__(16) u16 As8[8 * 4096];  // 64 KB: 8 windows x [128][32]
  __shared__ __align__(16) u16 Bs[2 * 4096];   // 16 KB: 2 windows
  const int bm = blockIdx.y * 128;
  const int bnq = blockIdx.x;                  // 0..3: 128-col quarter of 512
  const int tid = threadIdx.x, w = tid >> 6, l = tid & 63;
  const int wm = (w & 1) << 6, wn = (w >> 1) << 6;
  const int ln = l & 15, lq = l >> 4;
  const int sr0 = w * 16 + (l >> 2);
  const int sr1 = 64 + sr0;
  const int skp = (l & 3) * 8;
  const int skg = ((l & 3) ^ ((l >> 3) & 3)) * 8;
  const int kro = (lq ^ ((ln >> 1) & 3)) * 8;

  // stage all 8 A windows once (async; first barrier drains vmcnt)
#pragma unroll
  for (int kw = 0; kw < 8; kw++) {
    gld16(xb + (size_t)(bm + sr0) * 256 + kw * 32 + skg,
          As8 + kw * 4096 + sr0 * BK + skp);
    gld16(xb + (size_t)(bm + sr1) * 256 + kw * 32 + skg,
          As8 + kw * 4096 + sr1 * BK + skp);
  }

  const int b = bm >> 11, t0 = bm & 2047;
  const int cb = bnq * 128;

  for (int p = 0; p < 3; p++) {
    const u16* Bg = Wt + (size_t)(p * 512 + cb) * 256;
    f32x4 acc[4][4];
#pragma unroll
    for (int mt = 0; mt < 4; mt++)
#pragma unroll
      for (int nt = 0; nt < 4; nt++) acc[mt][nt] = (f32x4)0.0f;

#pragma unroll
    for (int it2 = 0; it2 < 4; it2++) {
      __syncthreads();
      gld16(Bg + (size_t)sr0 * 256 + it2 * 64 + skg, Bs + sr0 * BK + skp);
      gld16(Bg + (size_t)sr1 * 256 + it2 * 64 + skg, Bs + sr1 * BK + skp);
      gld16(Bg + (size_t)sr0 * 256 + it2 * 64 + 32 + skg,
            Bs + 4096 + sr0 * BK + skp);
      gld16(Bg + (size_t)sr1 * 256 + it2 * 64 + 32 + skg,
            Bs + 4096 + sr1 * BK + skp);
      __syncthreads();
#pragma unroll
      for (int h = 0; h < 2; h++) {
        const u16* Aw = As8 + (it2 * 2 + h) * 4096;
        const u16* Bh = Bs + h * 4096;
        short8 af[4], bf[4];
#pragma unroll
        for (int mt = 0; mt < 4; mt++)
          af[mt] = *(const short8*)(Aw + (wm + mt * 16 + ln) * BK + kro);
#pragma unroll
        for (int nt = 0; nt < 4; nt++)
          bf[nt] = *(const short8*)(Bh + (wn + nt * 16 + ln) * BK + kro);
#pragma unroll
        for (int mt = 0; mt < 4; mt++)
#pragma unroll
          for (int nt = 0; nt < 4; nt++)
            acc[mt][nt] = __builtin_amdgcn_mfma_f32_16x16x32_bf16(
                af[mt], bf[nt], acc[mt][nt], 0, 0, 0);
      }
    }

    if (p < 2) {
      u16* dst = p ? kb : qb;
#pragma unroll
      for (int mt = 0; mt < 4; mt++)
#pragma unroll
        for (int r = 0; r < 4; r++) {
          int row = bm + wm + mt * 16 + lq * 4 + r;
#pragma unroll
          for (int nt = 0; nt < 4; nt++) {
            int col = wn + nt * 16 + ln;
            float v = acc[mt][nt][r] + bcat[p * 512 + cb + col];
            float ov = (p == 0) ? __builtin_amdgcn_rcpf(1.0f + fexp(-v)) : v;
            dst[(size_t)row * 512 + cb + col] = f2bf(ov);
          }
        }
    } else {
      u16* tr = As8;                            // reuse dead A slab
#pragma unroll
      for (int h = 0; h < 2; h++) {
        __syncthreads();
        if ((w & 1) == h) {
#pragma unroll
          for (int mt = 0; mt < 4; mt++)
#pragma unroll
            for (int nt = 0; nt < 4; nt++) {
              int c = wn + nt * 16 + ln;
              float bias = bcat[1024 + cb + c];
#pragma unroll
              for (int r = 0; r < 4; r++) {
                int lr = mt * 16 + lq * 4 + r;
                tr[c * 68 + lr] = f2bf(acc[mt][nt][r] + bias);
              }
            }
        }
        __syncthreads();
        int c2 = tid >> 1, half = tid & 1;
        size_t dbase = ((size_t)b * 512 + cb + c2) * 2048 + t0 + h * 64 + half * 32;
#pragma unroll
        for (int j = 0; j < 4; j++) {
          ushort4 a0 = *(const ushort4*)&tr[c2 * 68 + half * 32 + j * 8];
          ushort4 a1 = *(const ushort4*)&tr[c2 * 68 + half * 32 + j * 8 + 4];
          *(ushort4*)&vtb[dbase + j * 8] = a0;
          *(ushort4*)&vtb[dbase + j * 8 + 4] = a1;
        }
      }
    }
  }
}

// ---------- QK^T + elu + exp -> P (bf16), row sums; XCD-swizzled ----------

__global__ __launch_bounds__(256, 4) void k_qk(const u16* __restrict__ qb,
                                               const u16* __restrict__ kb,
                                               u16* __restrict__ P,
                                               float* __restrict__ lsum) {
  __shared__ __align__(16) u16 As[2 * 4096];   // 16 KB (BK=64, 2 windows)
  __shared__ __align__(16) u16 Bs[2 * 4096];   // 16 KB
  // bid%8 = batch = XCD round-robin: each XCD's L2 keeps its batch's q+k (4MB)
  const int bid = blockIdx.x;
  const int b = bid & 7, t = bid >> 3;
  const int bm = (t >> 4) * 128, bn = (t & 15) * 128;
  const size_t ob = (size_t)b * 2048 * 512;
  const int tid = threadIdx.x, w = tid >> 6, l = tid & 63;
  f32x4 acc[4][4];
  gemm_core64(qb + ob + (size_t)bm * 512, kb + ob + (size_t)bn * 512,
              512, 512, 512, As, Bs, acc, w, l);

  const int wm = (w & 1) << 6, wn = (w >> 1) << 6;
  const int ln = l & 15, lq = l >> 4;
  const float scale = 0.0625f;  // 1/sqrt(256)
#pragma unroll
  for (int mt = 0; mt < 4; mt++)
#pragma unroll
    for (int r = 0; r < 4; r++) {
      int row = bm + wm + mt * 16 + lq * 4 + r;
      float s = 0.0f;
#pragma unroll
      for (int nt = 0; nt < 4; nt++) {
        int col = bn + wn + nt * 16 + ln;
        float v = acc[mt][nt][r] * scale;
        float e = (v > 0.0f) ? v : (fexp(v) - 1.0f);   // elu (hw exp)
        float p = fexp(e);    // unnormalized softmax (elu >= -1, no max sub)
        P[((size_t)b * 2048 + row) * 2048 + col] = f2bf(p);
        s += p;
      }
#pragma unroll
      for (int o = 1; o < 16; o <<= 1) s += __shfl_xor(s, o);
      if (ln == 0) atomicAdd(&lsum[b * 2048 + row], s);
    }
}

// ---------- P @ V, divide by row sum, fp32 out; XCD-swizzled ----------

__global__ __launch_bounds__(256, 4) void k_pv(const u16* __restrict__ P,
                                               const u16* __restrict__ vtb,
                                               const float* __restrict__ lsum,
                                               float* __restrict__ out) {
  __shared__ __align__(16) u16 As[2 * 4096];
  __shared__ __align__(16) u16 Bs[2 * 4096];
  // bid%8 = batch = XCD: vtb slab (2MB) L2-resident; bn fastest -> P-slab reuse
  const int bid = blockIdx.x;
  const int b = bid & 7, t = bid >> 3;
  const int bm = (t >> 2) * 128, bn = (t & 3) * 128;
  const int tid = threadIdx.x, w = tid >> 6, l = tid & 63;
  f32x4 acc[4][4];
  gemm_core64(P  + (size_t)b * 2048 * 2048 + (size_t)bm * 2048,
              vtb + (size_t)b * 512 * 2048 + (size_t)bn * 2048,
              2048, 2048, 2048, As, Bs, acc, w, l);

  const int wm = (w & 1) << 6, wn = (w >> 1) << 6;
  const int ln = l & 15, lq = l >> 4;
#pragma unroll
  for (int mt = 0; mt < 4; mt++)
#pragma unroll
    for (int r = 0; r < 4; r++) {
      int row = bm + wm + mt * 16 + lq * 4 + r;
      float inv = 1.0f / lsum[b * 2048 + row];
#pragma unroll
      for (int nt = 0; nt < 4; nt++) {
        int col = bn + wn + nt * 16 + ln;
        out[((size_t)b * 2048 + row) * 512 + col] = acc[mt][nt][r] * inv;
      }
    }
}

// ---------- launch ----------

extern "C" void kernel_launch(void* const* d_in, const int* in_sizes, int n_in,
                              void* d_out, int out_size, void* d_ws, size_t ws_size,
                              hipStream_t stream) {
  const float* x  = (const float*)d_in[0];
  const float* Wq = (const float*)d_in[1];
  const float* bq = (const float*)d_in[2];
  const float* Wk = (const float*)d_in[3];
  const float* bk = (const float*)d_in[4];
  const float* Wv = (const float*)d_in[5];
  const float* bv = (const float*)d_in[6];
  float* out = (float*)d_out;
  char* ws = (char*)d_ws;

  u16*  qb   = (u16*)(ws + 0);            // 16,777,216
  u16*  kb   = (u16*)(ws + 16777216);     // 16,777,216
  u16*  vtb  = (u16*)(ws + 33554432);     // 16,777,216
  float* lsum = (float*)(ws + 50331648);  //     65,536
  u16*  P    = (u16*)(ws + 50397184);     // 67,108,864 (ends 117,506,048)
  u16*  xb   = (u16*)(ws + 50397184);     //  8,388,608 (alias P)
  u16*  Wt   = (u16*)(ws + 58785792);     //    786,432 (alias P)
  float* bcat = (float*)(ws + 59572224);  //      6,144 (alias P)

  k_conv<<<5696, 256, 0, stream>>>(x, xb, Wq, Wk, Wv, bq, bk, bv, Wt, bcat, lsum);
  k_proj<<<dim3(4, 128, 1), 256, 0, stream>>>(xb, Wt, bcat, qb, kb, vtb);
  k_qk<<<2048, 256, 0, stream>>>(qb, kb, P, lsum);
  k_pv<<<512, 256, 0, stream>>>(P, vtb, lsum, out);
}